// Round 1
// baseline (1501.777 us; speedup 1.0000x reference)
//
#include <hip/hip_runtime.h>

#define EPS 1e-3f

// Tensor geometry (fixed for this problem):
// L1 out (y1): (2,16,21,256,256)  m1: (2,21,256,256)
// L2 out (h2): (2,32,11,128,128)  m2: (2,11,128,128)
// L3 out (h3): (2,64,5,64,64)     m3: (2,5,64,64)
// L4 out:      (2,64,2,64,64) -> d_out (2,128,64,64) same layout

// ---------------- Layer 1: voxel scatter into pre-activation accumulator ----------------
__global__ __launch_bounds__(256) void scatter_l1(
    const float* __restrict__ vf, const int* __restrict__ coors, int NV,
    const float* __restrict__ w1, float* __restrict__ y1, float* __restrict__ m1)
{
    __shared__ float ws[16 * 3 * 27];  // (oc, c, tap)
    for (int e = threadIdx.x; e < 16 * 3 * 27; e += 256) ws[e] = w1[e];
    __syncthreads();

    int i = blockIdx.x * 256 + threadIdx.x;
    if (i >= NV) return;

    const int b = coors[4 * i + 0];
    const int z = coors[4 * i + 1];
    const int y = coors[4 * i + 2];
    const int x = coors[4 * i + 3];
    const float f0 = vf[3 * i + 0];
    const float f1 = vf[3 * i + 1];
    const float f2 = vf[3 * i + 2];

    // input idx = 2*o + k - 1  ->  for each k, o = (coord+1-k)/2 when even & in range
    int ozv[2], kzv[2], nz = 0;
    int oyv[2], kyv[2], ny = 0;
    int oxv[2], kxv[2], nx = 0;
#pragma unroll
    for (int k = 0; k < 3; ++k) {
        int t = z + 1 - k;
        if (t >= 0 && !(t & 1)) { int o = t >> 1; if (o < 21) { ozv[nz] = o; kzv[nz] = k; ++nz; } }
    }
#pragma unroll
    for (int k = 0; k < 3; ++k) {
        int t = y + 1 - k;
        if (t >= 0 && !(t & 1)) { int o = t >> 1; if (o < 256) { oyv[ny] = o; kyv[ny] = k; ++ny; } }
    }
#pragma unroll
    for (int k = 0; k < 3; ++k) {
        int t = x + 1 - k;
        if (t >= 0 && !(t & 1)) { int o = t >> 1; if (o < 256) { oxv[nx] = o; kxv[nx] = k; ++nx; } }
    }

    for (int a = 0; a < nz; ++a)
        for (int bb = 0; bb < ny; ++bb)
            for (int c = 0; c < nx; ++c) {
                const int oz = ozv[a], oy = oyv[bb], ox = oxv[c];
                const int tap = (kzv[a] * 3 + kyv[bb]) * 3 + kxv[c];
                const int sp = ((b * 21 + oz) * 256 + oy) * 256 + ox;
                m1[sp] = 1.0f;
                const int base = (b * 16) * 1376256 + oz * 65536 + oy * 256 + ox;
#pragma unroll
                for (int oc = 0; oc < 16; ++oc) {
                    const float s = ws[oc * 81 + tap] * f0 + ws[oc * 81 + 27 + tap] * f1 +
                                    ws[oc * 81 + 54 + tap] * f2;
                    atomicAdd(&y1[base + oc * 1376256], s);
                }
            }
}

// ---------------- Layer 2: dense conv 16->32, k3, s2, pad(1,1,1) ----------------
// input virtual h1 = relu(y1*scale1+shift1)*m1 applied during staging.
__global__ __launch_bounds__(256) void conv_l2(
    const float* __restrict__ y1, const float* __restrict__ m1,
    const float* __restrict__ w2,
    const float* __restrict__ g1, const float* __restrict__ bb1,
    const float* __restrict__ rm1, const float* __restrict__ rv1,
    const float* __restrict__ g2, const float* __restrict__ bb2,
    const float* __restrict__ rm2, const float* __restrict__ rv2,
    float* __restrict__ h2, float* __restrict__ m2)
{
    __shared__ float sIn[3 * 17 * 65];
    __shared__ float sM[3 * 17 * 65];
    const int tid = threadIdx.x;
    const int tx = tid & 31, ty = tid >> 5;             // 32 x 8 spatial tile
    const int ox0 = blockIdx.x * 32, oy0 = blockIdx.y * 8;
    const int bz = blockIdx.z;
    const int b = bz / 11, oz = bz % 11;
    const int iz0 = 2 * oz - 1, iy0 = 2 * oy0 - 1, ix0 = 2 * ox0 - 1;

    // stage mask tile once
    for (int e = tid; e < 3 * 17 * 65; e += 256) {
        const int ez = e / (17 * 65), r = e % (17 * 65), ey = r / 65, ex = r % 65;
        const int iz = iz0 + ez, iy = iy0 + ey, ix = ix0 + ex;
        float mv = 0.f;
        if ((unsigned)iz < 21u && (unsigned)iy < 256u && (unsigned)ix < 256u)
            mv = m1[((b * 21 + iz) * 256 + iy) * 256 + ix];
        sM[e] = mv;
    }
    __syncthreads();

    float msum = 0.f;
#pragma unroll
    for (int kz = 0; kz < 3; ++kz)
#pragma unroll
        for (int ky = 0; ky < 3; ++ky)
#pragma unroll
            for (int kx = 0; kx < 3; ++kx)
                msum += sM[(kz * 17 + 2 * ty + ky) * 65 + 2 * tx + kx];
    const float mout = msum > 0.f ? 1.f : 0.f;

    float acc[32];
#pragma unroll
    for (int oc = 0; oc < 32; ++oc) acc[oc] = 0.f;

#pragma unroll 1
    for (int cin = 0; cin < 16; ++cin) {
        const float inv = g1[cin] * rsqrtf(rv1[cin] + EPS);
        const float sh = bb1[cin] - rm1[cin] * inv;
        for (int e = tid; e < 3 * 17 * 65; e += 256) {
            const int ez = e / (17 * 65), r = e % (17 * 65), ey = r / 65, ex = r % 65;
            const int iz = iz0 + ez, iy = iy0 + ey, ix = ix0 + ex;
            float v = 0.f;
            if ((unsigned)iz < 21u && (unsigned)iy < 256u && (unsigned)ix < 256u) {
                const float yv = y1[(((b * 16 + cin) * 21 + iz) * 256 + iy) * 256 + ix];
                v = fmaxf(yv * inv + sh, 0.f) * sM[e];
            }
            sIn[e] = v;
        }
        __syncthreads();

        float v[27];
#pragma unroll
        for (int kz = 0; kz < 3; ++kz)
#pragma unroll
            for (int ky = 0; ky < 3; ++ky)
#pragma unroll
                for (int kx = 0; kx < 3; ++kx)
                    v[(kz * 3 + ky) * 3 + kx] = sIn[(kz * 17 + 2 * ty + ky) * 65 + 2 * tx + kx];

#pragma unroll
        for (int oc = 0; oc < 32; ++oc) {
            const float* wp = w2 + (oc * 16 + cin) * 27;
#pragma unroll
            for (int t = 0; t < 27; ++t) acc[oc] = fmaf(wp[t], v[t], acc[oc]);
        }
        __syncthreads();
    }

    const int oy = oy0 + ty, ox = ox0 + tx;
    m2[((b * 11 + oz) * 128 + oy) * 128 + ox] = mout;
#pragma unroll
    for (int oc = 0; oc < 32; ++oc) {
        const float inv2 = g2[oc] * rsqrtf(rv2[oc] + EPS);
        const float sh2 = bb2[oc] - rm2[oc] * inv2;
        h2[(((b * 32 + oc) * 11 + oz) * 128 + oy) * 128 + ox] =
            fmaxf(acc[oc] * inv2 + sh2, 0.f) * mout;
    }
}

// ---------------- Layer 3: dense conv 32->64, k3, s2, pad(0,1,1); oc split in 2 ----------------
__global__ __launch_bounds__(256) void conv_l3(
    const float* __restrict__ h2, const float* __restrict__ m2,
    const float* __restrict__ w3,
    const float* __restrict__ g3, const float* __restrict__ bb3,
    const float* __restrict__ rm3, const float* __restrict__ rv3,
    float* __restrict__ h3, float* __restrict__ m3)
{
    __shared__ float sIn[3 * 17 * 65];
    __shared__ float sM[3 * 17 * 65];
    const int tid = threadIdx.x;
    const int tx = tid & 31, ty = tid >> 5;
    const int ox0 = blockIdx.x * 32, oy0 = blockIdx.y * 8;
    const int bz = blockIdx.z;
    const int b = bz / 10, r = bz % 10, oz = r >> 1, half = r & 1;
    const int iz0 = 2 * oz, iy0 = 2 * oy0 - 1, ix0 = 2 * ox0 - 1;  // z pad 0

    for (int e = tid; e < 3 * 17 * 65; e += 256) {
        const int ez = e / (17 * 65), rr = e % (17 * 65), ey = rr / 65, ex = rr % 65;
        const int iz = iz0 + ez, iy = iy0 + ey, ix = ix0 + ex;
        float mv = 0.f;
        if ((unsigned)iy < 128u && (unsigned)ix < 128u)  // iz always in [0,10]
            mv = m2[((b * 11 + iz) * 128 + iy) * 128 + ix];
        sM[e] = mv;
    }
    __syncthreads();

    float msum = 0.f;
#pragma unroll
    for (int kz = 0; kz < 3; ++kz)
#pragma unroll
        for (int ky = 0; ky < 3; ++ky)
#pragma unroll
            for (int kx = 0; kx < 3; ++kx)
                msum += sM[(kz * 17 + 2 * ty + ky) * 65 + 2 * tx + kx];
    const float mout = msum > 0.f ? 1.f : 0.f;

    float acc[32];
#pragma unroll
    for (int oc = 0; oc < 32; ++oc) acc[oc] = 0.f;

#pragma unroll 1
    for (int cin = 0; cin < 32; ++cin) {
        for (int e = tid; e < 3 * 17 * 65; e += 256) {
            const int ez = e / (17 * 65), rr = e % (17 * 65), ey = rr / 65, ex = rr % 65;
            const int iz = iz0 + ez, iy = iy0 + ey, ix = ix0 + ex;
            float v = 0.f;
            if ((unsigned)iy < 128u && (unsigned)ix < 128u)
                v = h2[(((b * 32 + cin) * 11 + iz) * 128 + iy) * 128 + ix];
            sIn[e] = v;
        }
        __syncthreads();

        float v[27];
#pragma unroll
        for (int kz = 0; kz < 3; ++kz)
#pragma unroll
            for (int ky = 0; ky < 3; ++ky)
#pragma unroll
                for (int kx = 0; kx < 3; ++kx)
                    v[(kz * 3 + ky) * 3 + kx] = sIn[(kz * 17 + 2 * ty + ky) * 65 + 2 * tx + kx];

#pragma unroll
        for (int oc = 0; oc < 32; ++oc) {
            const float* wp = w3 + ((half * 32 + oc) * 32 + cin) * 27;
#pragma unroll
            for (int t = 0; t < 27; ++t) acc[oc] = fmaf(wp[t], v[t], acc[oc]);
        }
        __syncthreads();
    }

    const int oy = oy0 + ty, ox = ox0 + tx;
    if (half == 0) m3[(b * 5 + oz) * 4096 + oy * 64 + ox] = mout;
#pragma unroll
    for (int oc = 0; oc < 32; ++oc) {
        const int ocg = half * 32 + oc;
        const float inv = g3[ocg] * rsqrtf(rv3[ocg] + EPS);
        const float sh = bb3[ocg] - rm3[ocg] * inv;
        h3[(((b * 64 + ocg) * 5 + oz) * 64 + oy) * 64 + ox] =
            fmaxf(acc[oc] * inv + sh, 0.f) * mout;
    }
}

// ---------------- Layer 4: conv 64->64, k(3,1,1), s(2,1,1), pad 0 ----------------
__global__ __launch_bounds__(256) void conv_l4(
    const float* __restrict__ h3, const float* __restrict__ m3,
    const float* __restrict__ w4,
    const float* __restrict__ g4, const float* __restrict__ bb4,
    const float* __restrict__ rm4, const float* __restrict__ rv4,
    float* __restrict__ out)
{
    const int p = blockIdx.x * 256 + threadIdx.x;  // 0..4095 spatial
    const int bo = blockIdx.y;
    const int b = bo >> 1, od = bo & 1;

    const float msum = m3[(b * 5 + 2 * od + 0) * 4096 + p] +
                       m3[(b * 5 + 2 * od + 1) * 4096 + p] +
                       m3[(b * 5 + 2 * od + 2) * 4096 + p];
    const float mout = msum > 0.f ? 1.f : 0.f;

    float acc[64];
#pragma unroll
    for (int oc = 0; oc < 64; ++oc) acc[oc] = 0.f;

#pragma unroll 1
    for (int c = 0; c < 64; ++c) {
        const float v0 = h3[((b * 64 + c) * 5 + 2 * od + 0) * 4096 + p];
        const float v1 = h3[((b * 64 + c) * 5 + 2 * od + 1) * 4096 + p];
        const float v2 = h3[((b * 64 + c) * 5 + 2 * od + 2) * 4096 + p];
#pragma unroll
        for (int oc = 0; oc < 64; ++oc) {
            const float* wp = w4 + (oc * 64 + c) * 3;
            acc[oc] = fmaf(wp[0], v0, fmaf(wp[1], v1, fmaf(wp[2], v2, acc[oc])));
        }
    }

#pragma unroll
    for (int oc = 0; oc < 64; ++oc) {
        const float inv = g4[oc] * rsqrtf(rv4[oc] + EPS);
        const float sh = bb4[oc] - rm4[oc] * inv;
        out[((b * 64 + oc) * 2 + od) * 4096 + p] = fmaxf(acc[oc] * inv + sh, 0.f) * mout;
    }
}

extern "C" void kernel_launch(void* const* d_in, const int* in_sizes, int n_in,
                              void* d_out, int out_size, void* d_ws, size_t ws_size,
                              hipStream_t stream)
{
    const float* vf    = (const float*)d_in[0];
    const int*   coors = (const int*)d_in[1];
    // d_in[2] = batch_size (==2, hardcoded in geometry)
    const float* w1 = (const float*)d_in[3];
    const float* g1 = (const float*)d_in[4];
    const float* b1 = (const float*)d_in[5];
    const float* rm1 = (const float*)d_in[6];
    const float* rv1 = (const float*)d_in[7];
    const float* w2 = (const float*)d_in[8];
    const float* g2 = (const float*)d_in[9];
    const float* b2 = (const float*)d_in[10];
    const float* rm2 = (const float*)d_in[11];
    const float* rv2 = (const float*)d_in[12];
    const float* w3 = (const float*)d_in[13];
    const float* g3 = (const float*)d_in[14];
    const float* b3 = (const float*)d_in[15];
    const float* rm3 = (const float*)d_in[16];
    const float* rv3 = (const float*)d_in[17];
    const float* w4 = (const float*)d_in[18];
    const float* g4 = (const float*)d_in[19];
    const float* b4 = (const float*)d_in[20];
    const float* rm4 = (const float*)d_in[21];
    const float* rv4 = (const float*)d_in[22];

    const int NV = in_sizes[0] / 3;

    float* ws = (float*)d_ws;
    float* y1 = ws;                    // 44,040,192 f  (2,16,21,256,256)
    float* m1 = y1 + 44040192;         //  2,752,512 f  (2,21,256,256)
    float* h2 = m1 + 2752512;          // 11,534,336 f  (2,32,11,128,128)
    float* m2 = h2 + 11534336;         //    360,448 f  (2,11,128,128)
    float* h3 = m2 + 360448;           //  2,621,440 f  (2,64,5,64,64)
    float* m3 = h3 + 2621440;          //     40,960 f  (2,5,64,64)

    // zero the scatter accumulator + mask (y1 and m1 are contiguous)
    hipMemsetAsync(y1, 0, (size_t)(44040192 + 2752512) * sizeof(float), stream);

    scatter_l1<<<(NV + 255) / 256, 256, 0, stream>>>(vf, coors, NV, w1, y1, m1);
    conv_l2<<<dim3(4, 16, 22), 256, 0, stream>>>(y1, m1, w2, g1, b1, rm1, rv1,
                                                 g2, b2, rm2, rv2, h2, m2);
    conv_l3<<<dim3(2, 8, 20), 256, 0, stream>>>(h2, m2, w3, g3, b3, rm3, rv3, h3, m3);
    conv_l4<<<dim3(16, 4), 256, 0, stream>>>(h3, m3, w4, g4, b4, rm4, rv4, (float*)d_out);
}